// Round 11
// baseline (1002.268 us; speedup 1.0000x reference)
//
#include <hip/hip_runtime.h>
#include <hip/hip_bf16.h>
#include <stdint.h>

// Problem constants (QKVParallelLinearWithLoRA)
#define S_TOK 16384
#define DIN   4096
#define OUTQ  4096
#define OUTKV 1024
#define NOUT  6144   // OUTQ + 2*OUTKV
#define LRANK 64

typedef __attribute__((ext_vector_type(8))) short bf16x8;           // 8 bf16 = 4 VGPR
typedef __attribute__((ext_vector_type(4))) float f32x4;            // MFMA acc frag
typedef __attribute__((ext_vector_type(4))) unsigned short u16x4;   // 4 bf16 store

static __device__ __forceinline__ unsigned short f2bf(float f) {
  uint32_t u = __float_as_uint(f);
  u += 0x7FFFu + ((u >> 16) & 1u);
  return (unsigned short)(u >> 16);
}

static __device__ __forceinline__ void gload_lds16(const void* g, void* l) {
  __builtin_amdgcn_global_load_lds((const __attribute__((address_space(1))) void*)g,
                                   (__attribute__((address_space(3))) void*)l,
                                   16, 0, 0);
}

// ---------------------------------------------------------------------------
// Kernel 1+2 FUSED: blocks [0,3072) do prep_weff; blocks [3072,5120) do
// x fp32->bf16. Independent work, one dispatch -> the two HBM streams run
// concurrently (was ~65+50 us serialized; combined 528MB ~ 85 us).
// ---------------------------------------------------------------------------
__global__ __launch_bounds__(256) void prep_fused(const float* __restrict__ x,
                                                  const float* __restrict__ W,
                                                  const float* __restrict__ A,
                                                  const float* __restrict__ Bq,
                                                  const float* __restrict__ Bk,
                                                  const float* __restrict__ Bv,
                                                  unsigned short* __restrict__ xb,
                                                  unsigned short* __restrict__ Weff) {
  const int bid = blockIdx.x;
  const int t = threadIdx.x;

  if (bid >= 3072) {
    // ---- cvt path: 2048 blocks, grid-stride float4 -> 4x bf16
    const int n4 = S_TOK * DIN / 4;
    const int stride = 2048 * 256;
    const float4* in4 = (const float4*)x;
    for (int i = (bid - 3072) * 256 + t; i < n4; i += stride) {
      float4 v = in4[i];
      u16x4 o;
      o.x = f2bf(v.x); o.y = f2bf(v.y); o.z = f2bf(v.z); o.w = f2bf(v.w);
      *(u16x4*)(xb + (size_t)i * 4) = o;
    }
    return;
  }

  // ---- prep path: W_eff[o][d] = W[o][d] + sum_r B_seg[o'][r]*A[seg*64+r][d]
  __shared__ float As_[64][128];
  __shared__ float Bs_[64][64];
  const int o0 = (bid % 96) * 64;
  const int d0 = (bid / 96) * 128;

  const float* Bseg; int seg, ob;
  if (o0 < OUTQ)              { seg = 0; Bseg = Bq; ob = o0; }
  else if (o0 < OUTQ + OUTKV) { seg = 1; Bseg = Bk; ob = o0 - OUTQ; }
  else                        { seg = 2; Bseg = Bv; ob = o0 - OUTQ - OUTKV; }

  {
    const float4* src = (const float4*)(Bseg + (size_t)ob * LRANK);
    float4* dst = (float4*)&Bs_[0][0];
    for (int i = t; i < 64 * 64 / 4; i += 256) dst[i] = src[i];
  }
  for (int i = t; i < 64 * 32; i += 256) {
    int r = i >> 5, c4 = i & 31;
    *(float4*)&As_[r][c4 * 4] =
        *(const float4*)(A + (size_t)(seg * 64 + r) * DIN + d0 + c4 * 4);
  }
  __syncthreads();

  const int tx = t & 31;
  const int tg = t >> 5;
  for (int oi = tg * 8; oi < tg * 8 + 8; ++oi) {
    const int o = o0 + oi;
    float4 acc = *(const float4*)(W + (size_t)o * DIN + d0 + tx * 4);
#pragma unroll 8
    for (int r = 0; r < 64; ++r) {
      const float b = Bs_[oi][r];
      const float4 a = *(const float4*)&As_[r][tx * 4];
      acc.x += b * a.x; acc.y += b * a.y; acc.z += b * a.z; acc.w += b * a.w;
    }
    u16x4 ov;
    ov.x = f2bf(acc.x); ov.y = f2bf(acc.y); ov.z = f2bf(acc.z); ov.w = f2bf(acc.w);
    *(u16x4*)(Weff + (size_t)o * DIN + d0 + tx * 4) = ov;
  }
}

// ---------------------------------------------------------------------------
// Kernel 3: 256x256 GEMM, BK=64, 4 WAVES x (128x128) wave tile, loose
// 2-phase windows (R10 structure).
//   C[m,n] = sum_k Xb[m,k]*Wb[n,k] + bias[n]
// Rationale (R10 cycle model, exact fit 1193 ~ 1190 measured): phase = DS
// reads 48KB/128Bcyc (384) + LDS writes (128) + MFMA/SIMD (621) + ~60,
// fully serialized (convoy immovable across R2/R5/R6/R9/R10). This round
// shrinks the DS-read term: 4 waves x (128x128) reads 16 b128 per 64 MFMA
// vs 8 waves x (128x64) reading 12 per 32 -- per-CU reads/phase 48KB->32KB.
// MFMA/SIMD unchanged (1 wave x 32 = 2 x 16). acc[8][8] f32x4 = 256 VGPR
// + af[8] + bq[4] ~ 360 regs -> 1 wave/SIMD, no spill (all static indices).
// Phase (buf,ks,nh): [nh==0: read af[0..7]]; read bq[0..3] (ni-half nh);
// stage one half-tile (4 gload_lds); setprio(1); 32 MFMA; setprio(0);
// [even phases: vmcnt(8)+barrier -- counted, never 0 in main loop].
// Ledger = R4/R10's verified rotation with 4-load half-tiles (counts x2):
// at each V8, outstanding = 2 half-tiles(8), everything older landed; WAR
// separated by >=1 even barrier; peel drains 8 -> 8 -> 0.
// Swizzle: byte ^= ((row>>1)&3)<<4 inverse-applied to global source (rule
// #21), 0 conflicts measured R4-R10. Rectangle XCD swizzle (FETCH 3.2x).
// ---------------------------------------------------------------------------
__global__ __launch_bounds__(256, 1) void gemm_bt_bias(const unsigned short* __restrict__ Xb,
                                                       const unsigned short* __restrict__ Wb,
                                                       const float* __restrict__ bias,
                                                       float* __restrict__ C) {
  __shared__ unsigned short Alds[32768];  // [buf][kh][256 rows][32 k] = 4x16KB
  __shared__ unsigned short Blds[32768];

  const int bid = blockIdx.x;
  const int x = bid & 7;
  const int l = bid >> 3;
  const int g = l >> 5;
  const int i5 = l & 31;
  const int mt = x * 8 + (i5 & 7);
  const int nt = g * 4 + (i5 >> 3);
  const int m0 = mt * 256;
  const int n0 = nt * 256;

  const int t = threadIdx.x;
  const int lane = t & 63;
  const int w = t >> 6;                   // 0..3
  const int wm = (w >> 1) * 128;          // 2 waves in M
  const int wn = (w & 1) * 128;           // 2 waves in N

  // staging: 256 threads; one gload_lds16 covers 64 rows (4KB). trow = t>>2,
  // phys 16B-slot t&3; logical k-slot = (t&3)^((trow>>1)&3) (row bits 1-2
  // == trow bits 1-2 since chunk offsets are multiples of 64). 4 instrs per
  // half-tile, row chunk j*64.
  const int trow = t >> 2;
  const int ksl = (t & 3) ^ ((trow >> 1) & 3);
  size_t gA[4], gB[4];
#pragma unroll
  for (int j = 0; j < 4; ++j) {
    gA[j] = (size_t)(m0 + j * 64 + trow) * DIN + ksl * 8;
    gB[j] = (size_t)(n0 + j * 64 + trow) * DIN + ksl * 8;
  }
  const int ldst = t * 8;                 // element offset within 4KB chunk

#define STAGE_A(T, kh) do {                                                   \
    const int rb_ = (((T) & 1) * 2 + (kh)) * 8192;                            \
    const size_t ko_ = (size_t)((T) * 64 + (kh) * 32);                        \
    gload_lds16(Xb + gA[0] + ko_, &Alds[rb_ + 0 * 2048 + ldst]);              \
    gload_lds16(Xb + gA[1] + ko_, &Alds[rb_ + 1 * 2048 + ldst]);              \
    gload_lds16(Xb + gA[2] + ko_, &Alds[rb_ + 2 * 2048 + ldst]);              \
    gload_lds16(Xb + gA[3] + ko_, &Alds[rb_ + 3 * 2048 + ldst]);              \
  } while (0)
#define STAGE_B(T, kh) do {                                                   \
    const int rb_ = (((T) & 1) * 2 + (kh)) * 8192;                            \
    const size_t ko_ = (size_t)((T) * 64 + (kh) * 32);                        \
    gload_lds16(Wb + gB[0] + ko_, &Blds[rb_ + 0 * 2048 + ldst]);              \
    gload_lds16(Wb + gB[1] + ko_, &Blds[rb_ + 1 * 2048 + ldst]);              \
    gload_lds16(Wb + gB[2] + ko_, &Blds[rb_ + 2 * 2048 + ldst]);              \
    gload_lds16(Wb + gB[3] + ko_, &Blds[rb_ + 3 * 2048 + ldst]);              \
  } while (0)

  // fragment read offsets (bytes within a 16KB region): row = base + lr,
  // 16B at (lane>>4)*16, swizzle-xor is a per-lane constant.
  const int lr = lane & 15;
  const int ks16 = (lane >> 4) * 16;
  const int fxor = ((lr >> 1) & 3) << 4;
  const int aoff = ((wm + lr) * 64 + ks16) ^ fxor;   // + mi*1024
  const int boff = ((wn + lr) * 64 + ks16) ^ fxor;   // + nh*4096 + ni*1024

  f32x4 acc[8][8];
#pragma unroll
  for (int i = 0; i < 8; ++i)
#pragma unroll
    for (int j = 0; j < 8; ++j)
      acc[i][j] = f32x4{0.f, 0.f, 0.f, 0.f};
  bf16x8 af[8];

#define END_N()  ((void)0)
#define END_V8() do { asm volatile("s_waitcnt vmcnt(8)" ::: "memory");        \
                      __builtin_amdgcn_s_barrier(); } while (0)
#define END_V0() do { asm volatile("s_waitcnt vmcnt(0)" ::: "memory");        \
                      __builtin_amdgcn_s_barrier(); } while (0)

  // PH(buf, ks, nh): [nh0: af[0..7]]; bq[0..3] (ni-half nh); stage; 32 MFMA.
#define PH(buf, ks, nh, STAGE_STMT, ENDM) do {                                \
    const char* Ar_ = (const char*)&Alds[((buf) * 2 + (ks)) * 8192];          \
    const char* Br_ = (const char*)&Blds[((buf) * 2 + (ks)) * 8192];          \
    bf16x8 bq_[4];                                                            \
    if ((nh) == 0) {                                                          \
      _Pragma("unroll")                                                       \
      for (int m_ = 0; m_ < 8; ++m_)                                          \
        af[m_] = *(const bf16x8*)(Ar_ + aoff + m_ * 1024);                    \
    }                                                                         \
    _Pragma("unroll")                                                         \
    for (int n_ = 0; n_ < 4; ++n_)                                            \
      bq_[n_] = *(const bf16x8*)(Br_ + boff + (nh) * 4096 + n_ * 1024);       \
    STAGE_STMT;                                                               \
    __builtin_amdgcn_s_setprio(1);                                            \
    _Pragma("unroll")                                                         \
    for (int m_ = 0; m_ < 8; ++m_)                                            \
      _Pragma("unroll")                                                       \
      for (int n_ = 0; n_ < 4; ++n_)                                          \
        acc[m_][(nh) * 4 + n_] = __builtin_amdgcn_mfma_f32_16x16x32_bf16(     \
            af[m_], bq_[n_], acc[m_][(nh) * 4 + n_], 0, 0, 0);                \
    __builtin_amdgcn_s_setprio(0);                                            \
    ENDM();                                                                   \
  } while (0)

  // prologue: stage tile 0 fully (16 loads, order A0,B0,A1,B1); wait oldest 8.
  STAGE_A(0, 0); STAGE_B(0, 0); STAGE_A(0, 1); STAGE_B(0, 1);
  END_V8();

  // main loop: 31 iterations, tiles 0..61; tile 62 staged by i=30 phases 5-8.
  // Rotation and ledger = R4/R10 (race-free across R4,R5,R9,R10), loads x2.
  for (int i = 0; i < 31; ++i) {
    const int T1 = 2 * i + 1, T2 = 2 * i + 2;
    PH(0, 0, 0, STAGE_A(T1, 0), END_N);   // p1
    PH(0, 0, 1, STAGE_B(T1, 0), END_V8);  // p2: tile2i A1,B1 land
    PH(0, 1, 0, STAGE_A(T1, 1), END_N);   // p3
    PH(0, 1, 1, STAGE_B(T1, 1), END_V8);  // p4: tile2i+1 A0,B0 land
    PH(1, 0, 0, STAGE_A(T2, 0), END_N);   // p5
    PH(1, 0, 1, STAGE_B(T2, 0), END_V8);  // p6: tile2i+1 A1,B1 land
    PH(1, 1, 0, STAGE_A(T2, 1), END_N);   // p7
    PH(1, 1, 1, STAGE_B(T2, 1), END_V8);  // p8: tile2i+2 A0,B0 land
  }
  // final iteration (tiles 62, 63): stage only tile 63; drain 8 -> 8 -> 0.
  PH(0, 0, 0, STAGE_A(63, 0), END_N);
  PH(0, 0, 1, STAGE_B(63, 0), END_V8);    // tile62 A1,B1 land
  PH(0, 1, 0, STAGE_A(63, 1), END_N);
  PH(0, 1, 1, STAGE_B(63, 1), END_V8);    // tile63 A0,B0 land
  PH(1, 0, 0, ((void)0), END_N);
  PH(1, 0, 1, ((void)0), END_V0);         // tile63 A1,B1 land
  PH(1, 1, 0, ((void)0), END_N);
  PH(1, 1, 1, ((void)0), END_N);

#undef PH
#undef STAGE_A
#undef STAGE_B
#undef END_N
#undef END_V8
#undef END_V0

  // epilogue: C/D layout col=lane&15, row=(lane>>4)*4+reg (m89/m91-verified)
  const int cr4 = (lane >> 4) * 4;
#pragma unroll
  for (int ni = 0; ni < 8; ++ni) {
    const int col = n0 + wn + ni * 16 + lr;
    const float bv = bias[col];
#pragma unroll
    for (int mi = 0; mi < 8; ++mi) {
      const int row = m0 + wm + mi * 16 + cr4;
#pragma unroll
      for (int jj = 0; jj < 4; ++jj)
        C[(size_t)(row + jj) * NOUT + col] = acc[mi][ni][jj] + bv;
    }
  }
}

// ---------------------------------------------------------------------------
extern "C" void kernel_launch(void* const* d_in, const int* in_sizes, int n_in,
                              void* d_out, int out_size, void* d_ws, size_t ws_size,
                              hipStream_t stream) {
  const float* x    = (const float*)d_in[0];
  const float* Wqkv = (const float*)d_in[1];
  const float* bias = (const float*)d_in[2];
  const float* Aq   = (const float*)d_in[3];
  const float* Bq   = (const float*)d_in[4];
  const float* Bk   = (const float*)d_in[5];
  const float* Bv   = (const float*)d_in[6];
  float* out = (float*)d_out;

  unsigned short* xb = (unsigned short*)d_ws;                 // 128 MB
  unsigned short* wb = xb + (size_t)S_TOK * DIN;              // 48 MB

  prep_fused<<<5120, 256, 0, stream>>>(x, Wqkv, Aq, Bq, Bk, Bv, xb, wb);

  gemm_bt_bias<<<1536, 256, 0, stream>>>(xb, wb, bias, out);
}

// Round 12
// 886.537 us; speedup vs baseline: 1.1305x; 1.1305x over previous
//
#include <hip/hip_runtime.h>
#include <hip/hip_bf16.h>
#include <stdint.h>

// Problem constants (QKVParallelLinearWithLoRA)
#define S_TOK 16384
#define DIN   4096
#define OUTQ  4096
#define OUTKV 1024
#define NOUT  6144   // OUTQ + 2*OUTKV
#define LRANK 64

typedef __attribute__((ext_vector_type(8))) short bf16x8;           // 8 bf16 = 4 VGPR
typedef __attribute__((ext_vector_type(4))) float f32x4;            // MFMA acc frag
typedef __attribute__((ext_vector_type(4))) unsigned short u16x4;   // 4 bf16 store

static __device__ __forceinline__ unsigned short f2bf(float f) {
  uint32_t u = __float_as_uint(f);
  u += 0x7FFFu + ((u >> 16) & 1u);
  return (unsigned short)(u >> 16);
}

static __device__ __forceinline__ void gload_lds16(const void* g, void* l) {
  __builtin_amdgcn_global_load_lds((const __attribute__((address_space(1))) void*)g,
                                   (__attribute__((address_space(3))) void*)l,
                                   16, 0, 0);
}

// ---------------------------------------------------------------------------
// Kernel 1+2 FUSED (R11, kept: saved ~42us): blocks [0,3072) prep_weff;
// blocks [3072,5120) x fp32->bf16. Independent work, concurrent HBM streams.
// ---------------------------------------------------------------------------
__global__ __launch_bounds__(256) void prep_fused(const float* __restrict__ x,
                                                  const float* __restrict__ W,
                                                  const float* __restrict__ A,
                                                  const float* __restrict__ Bq,
                                                  const float* __restrict__ Bk,
                                                  const float* __restrict__ Bv,
                                                  unsigned short* __restrict__ xb,
                                                  unsigned short* __restrict__ Weff) {
  const int bid = blockIdx.x;
  const int t = threadIdx.x;

  if (bid >= 3072) {
    const int n4 = S_TOK * DIN / 4;
    const int stride = 2048 * 256;
    const float4* in4 = (const float4*)x;
    for (int i = (bid - 3072) * 256 + t; i < n4; i += stride) {
      float4 v = in4[i];
      u16x4 o;
      o.x = f2bf(v.x); o.y = f2bf(v.y); o.z = f2bf(v.z); o.w = f2bf(v.w);
      *(u16x4*)(xb + (size_t)i * 4) = o;
    }
    return;
  }

  __shared__ float As_[64][128];
  __shared__ float Bs_[64][64];
  const int o0 = (bid % 96) * 64;
  const int d0 = (bid / 96) * 128;

  const float* Bseg; int seg, ob;
  if (o0 < OUTQ)              { seg = 0; Bseg = Bq; ob = o0; }
  else if (o0 < OUTQ + OUTKV) { seg = 1; Bseg = Bk; ob = o0 - OUTQ; }
  else                        { seg = 2; Bseg = Bv; ob = o0 - OUTQ - OUTKV; }

  {
    const float4* src = (const float4*)(Bseg + (size_t)ob * LRANK);
    float4* dst = (float4*)&Bs_[0][0];
    for (int i = t; i < 64 * 64 / 4; i += 256) dst[i] = src[i];
  }
  for (int i = t; i < 64 * 32; i += 256) {
    int r = i >> 5, c4 = i & 31;
    *(float4*)&As_[r][c4 * 4] =
        *(const float4*)(A + (size_t)(seg * 64 + r) * DIN + d0 + c4 * 4);
  }
  __syncthreads();

  const int tx = t & 31;
  const int tg = t >> 5;
  for (int oi = tg * 8; oi < tg * 8 + 8; ++oi) {
    const int o = o0 + oi;
    float4 acc = *(const float4*)(W + (size_t)o * DIN + d0 + tx * 4);
#pragma unroll 8
    for (int r = 0; r < 64; ++r) {
      const float b = Bs_[oi][r];
      const float4 a = *(const float4*)&As_[r][tx * 4];
      acc.x += b * a.x; acc.y += b * a.y; acc.z += b * a.z; acc.w += b * a.w;
    }
    u16x4 ov;
    ov.x = f2bf(acc.x); ov.y = f2bf(acc.y); ov.z = f2bf(acc.z); ov.w = f2bf(acc.w);
    *(u16x4*)(Weff + (size_t)o * DIN + d0 + tx * 4) = ov;
  }
}

// ---------------------------------------------------------------------------
// Kernel 3: 256x256 GEMM, BK=64, 8 waves x (128x64), loose 2-phase windows
// -- EXACT R10 configuration (measured best: 755-775us, MfmaUtil 51%,
// 0 bank conflicts, FETCH 0.59GB). R11's 4-wave x (128x128) regressed
// (1 wave/SIMD -> no TLP); reverted.
//   C[m,n] = sum_k Xb[m,k]*Wb[n,k] + bias[n]
// Barriers only at even-phase ends with counted vmcnt(4) (never 0 in main
// loop). Within a 2-phase window the compiler interleaves 12 ds_read_b128
// + 32 MFMA with fine-grained lgkm waits. Ledger (verified R4/R9/R10):
// RAW -- vmcnt(4) lands each region one window before its reads; WAR --
// every stage separated from prior readers by >=1 even barrier; tail drains
// 4->4->0. Swizzle: byte ^= ((row>>1)&3)<<4 inverse-applied to the GLOBAL
// source (linear gload_lds dest, rule #21). 2-D co-residency XCD swizzle:
// per-XCD 8mt x 4nt rectangle (FETCH 3.2x lower than 1-D).
// ---------------------------------------------------------------------------
__global__ __launch_bounds__(512, 1) void gemm_bt_bias(const unsigned short* __restrict__ Xb,
                                                       const unsigned short* __restrict__ Wb,
                                                       const float* __restrict__ bias,
                                                       float* __restrict__ C) {
  __shared__ unsigned short Alds[32768];  // [buf][kh][256 rows][32 k] = 4x16KB
  __shared__ unsigned short Blds[32768];

  const int bid = blockIdx.x;
  const int x = bid & 7;
  const int l = bid >> 3;
  const int g = l >> 5;
  const int i5 = l & 31;
  const int mt = x * 8 + (i5 & 7);
  const int nt = g * 4 + (i5 >> 3);
  const int m0 = mt * 256;
  const int n0 = nt * 256;

  const int t = threadIdx.x;
  const int lane = t & 63;
  const int w = t >> 6;
  const int wm = (w >> 2) * 128;          // 2 waves in M
  const int wn = (w & 3) * 64;            // 4 waves in N

  const int trow = t >> 2;
  const int ksl = (t & 3) ^ ((trow >> 1) & 3);
  const size_t gA0 = (size_t)(m0 + trow) * DIN + ksl * 8;
  const size_t gA1 = (size_t)(m0 + 128 + trow) * DIN + ksl * 8;
  const size_t gB0 = (size_t)(n0 + trow) * DIN + ksl * 8;
  const size_t gB1 = (size_t)(n0 + 128 + trow) * DIN + ksl * 8;
  const int ldst = t * 8;

#define STAGE_A(T, kh) do {                                                   \
    const int rb_ = (((T) & 1) * 2 + (kh)) * 8192;                            \
    const size_t ko_ = (size_t)((T) * 64 + (kh) * 32);                        \
    gload_lds16(Xb + gA0 + ko_, &Alds[rb_ + ldst]);                           \
    gload_lds16(Xb + gA1 + ko_, &Alds[rb_ + 4096 + ldst]);                    \
  } while (0)
#define STAGE_B(T, kh) do {                                                   \
    const int rb_ = (((T) & 1) * 2 + (kh)) * 8192;                            \
    const size_t ko_ = (size_t)((T) * 64 + (kh) * 32);                        \
    gload_lds16(Wb + gB0 + ko_, &Blds[rb_ + ldst]);                           \
    gload_lds16(Wb + gB1 + ko_, &Blds[rb_ + 4096 + ldst]);                    \
  } while (0)

  const int lr = lane & 15;
  const int ks16 = (lane >> 4) * 16;
  const int fxor = ((lr >> 1) & 3) << 4;
  const int aoff = ((wm + lr) * 64 + ks16) ^ fxor;
  const int boff = ((wn + lr) * 64 + ks16) ^ fxor;

  f32x4 acc[8][4];
#pragma unroll
  for (int i = 0; i < 8; ++i)
#pragma unroll
    for (int j = 0; j < 4; ++j)
      acc[i][j] = f32x4{0.f, 0.f, 0.f, 0.f};
  bf16x8 bq[4];

#define END_N()  ((void)0)                 // odd phase: no terminator
#define END_V4() do { asm volatile("s_waitcnt vmcnt(4)" ::: "memory");        \
                      __builtin_amdgcn_s_barrier(); } while (0)
#define END_V0() do { asm volatile("s_waitcnt vmcnt(0)" ::: "memory");        \
                      __builtin_amdgcn_s_barrier(); } while (0)

#define PH(buf, ks, fh, STAGE_STMT, ENDM) do {                                \
    const char* Ar_ = (const char*)&Alds[((buf) * 2 + (ks)) * 8192];          \
    const char* Br_ = (const char*)&Blds[((buf) * 2 + (ks)) * 8192];          \
    bf16x8 af_[4];                                                            \
    if ((fh) == 0) {                                                          \
      _Pragma("unroll")                                                       \
      for (int n_ = 0; n_ < 4; ++n_)                                          \
        bq[n_] = *(const bf16x8*)(Br_ + boff + n_ * 1024);                    \
    }                                                                         \
    _Pragma("unroll")                                                         \
    for (int j_ = 0; j_ < 4; ++j_)                                            \
      af_[j_] = *(const bf16x8*)(Ar_ + aoff + ((fh) * 4 + j_) * 1024);        \
    STAGE_STMT;                                                               \
    __builtin_amdgcn_s_setprio(1);                                            \
    _Pragma("unroll")                                                         \
    for (int j_ = 0; j_ < 4; ++j_)                                            \
      _Pragma("unroll")                                                       \
      for (int n_ = 0; n_ < 4; ++n_)                                          \
        acc[(fh) * 4 + j_][n_] = __builtin_amdgcn_mfma_f32_16x16x32_bf16(     \
            af_[j_], bq[n_], acc[(fh) * 4 + j_][n_], 0, 0, 0);                \
    __builtin_amdgcn_s_setprio(0);                                            \
    ENDM();                                                                   \
  } while (0)

  // prologue: stage tile 0 fully (8 loads, order A0,B0,A1,B1); wait oldest 4.
  STAGE_A(0, 0); STAGE_B(0, 0); STAGE_A(0, 1); STAGE_B(0, 1);
  END_V4();

  // main loop: 31 iterations, tiles 0..61; tile 62 staged by i=30 phases 5-8.
  for (int i = 0; i < 31; ++i) {
    const int T1 = 2 * i + 1, T2 = 2 * i + 2;
    PH(0, 0, 0, STAGE_A(T1, 0), END_N);   // p1
    PH(0, 0, 1, STAGE_B(T1, 0), END_V4);  // p2: tile2i A1,B1 land
    PH(0, 1, 0, STAGE_A(T1, 1), END_N);   // p3
    PH(0, 1, 1, STAGE_B(T1, 1), END_V4);  // p4: tile2i+1 A0,B0 land
    PH(1, 0, 0, STAGE_A(T2, 0), END_N);   // p5
    PH(1, 0, 1, STAGE_B(T2, 0), END_V4);  // p6: tile2i+1 A1,B1 land
    PH(1, 1, 0, STAGE_A(T2, 1), END_N);   // p7
    PH(1, 1, 1, STAGE_B(T2, 1), END_V4);  // p8: tile2i+2 A0,B0 land
  }
  // final iteration (tiles 62, 63): stage only tile 63; drain 4 -> 4 -> 0.
  PH(0, 0, 0, STAGE_A(63, 0), END_N);
  PH(0, 0, 1, STAGE_B(63, 0), END_V4);    // tile62 A1,B1 land
  PH(0, 1, 0, STAGE_A(63, 1), END_N);
  PH(0, 1, 1, STAGE_B(63, 1), END_V4);    // tile63 A0,B0 land
  PH(1, 0, 0, ((void)0), END_N);
  PH(1, 0, 1, ((void)0), END_V0);         // tile63 A1,B1 land
  PH(1, 1, 0, ((void)0), END_N);
  PH(1, 1, 1, ((void)0), END_N);          // no barrier needed before epilogue

#undef PH
#undef STAGE_A
#undef STAGE_B
#undef END_N
#undef END_V4
#undef END_V0

  // epilogue: C/D layout col=lane&15, row=(lane>>4)*4+reg (m89/m91-verified)
  const int cr4 = (lane >> 4) * 4;
#pragma unroll
  for (int ni = 0; ni < 4; ++ni) {
    const int col = n0 + wn + ni * 16 + lr;
    const float bv = bias[col];
#pragma unroll
    for (int mi = 0; mi < 8; ++mi) {
      const int row = m0 + wm + mi * 16 + cr4;
#pragma unroll
      for (int jj = 0; jj < 4; ++jj)
        C[(size_t)(row + jj) * NOUT + col] = acc[mi][ni][jj] + bv;
    }
  }
}

// ---------------------------------------------------------------------------
extern "C" void kernel_launch(void* const* d_in, const int* in_sizes, int n_in,
                              void* d_out, int out_size, void* d_ws, size_t ws_size,
                              hipStream_t stream) {
  const float* x    = (const float*)d_in[0];
  const float* Wqkv = (const float*)d_in[1];
  const float* bias = (const float*)d_in[2];
  const float* Aq   = (const float*)d_in[3];
  const float* Bq   = (const float*)d_in[4];
  const float* Bk   = (const float*)d_in[5];
  const float* Bv   = (const float*)d_in[6];
  float* out = (float*)d_out;

  unsigned short* xb = (unsigned short*)d_ws;                 // 128 MB
  unsigned short* wb = xb + (size_t)S_TOK * DIN;              // 48 MB

  prep_fused<<<5120, 256, 0, stream>>>(x, Wqkv, Aq, Bq, Bk, Bv, xb, wb);

  gemm_bt_bias<<<1536, 512, 0, stream>>>(xb, wb, bias, out);
}